// Round 2
// 100.207 us; speedup vs baseline: 1.0163x; 1.0163x over previous
//
#include <hip/hip_runtime.h>

#define N_Q     40000
#define N_S     40000
#define KK      32
#define PP      15
#define IN_DIM  64
#define OUT_DIM 128

typedef __attribute__((ext_vector_type(8))) short short8;   // 8 bf16 (A/B frag)
typedef __attribute__((ext_vector_type(4))) float floatx4;  // mfma C/D frag

// float -> bf16 bits, round-to-nearest-even
static __device__ __forceinline__ short f2bf(float f) {
  union { float f; unsigned u; } v; v.f = f;
  unsigned r = v.u + 0x7FFFu + ((v.u >> 16) & 1u);
  return (short)(r >> 16);
}

// ws layout:
//   packed : (N_S+1) float4 @ 0        (sx,sy,sz,valid; last entry = shadow zeros)
//   wmf    : 240 KB @ 1 MiB            (W as bf16, pre-swizzled into mfma B-frags:
//            frag fi=(p*8+g)*2+kc holds B[n=lane&15][k=kc*32+quad*8+j] = W[p][k][g*16+n])
//   r2     : 1 float @ 1 MiB + 256 KiB (candidate radius^2 = (max_p|kp| + 0.05)^2)

// Kernel 1: blocks [0,2500): rowsum -> valid flag + packed float4 point table.
//           blocks [2500,2740): swizzle W fp32 -> bf16 mfma B-fragment layout.
//           block 2740: compute R2 once (removes a 6-shfl serial dependency
//                       chain from every wave of the hot kernel).
__global__ __launch_bounds__(256) void prep_kernel(
    const float* __restrict__ x, const float* __restrict__ s_pts,
    const float* __restrict__ weights, const float* __restrict__ kpts,
    float4* __restrict__ packed, unsigned* __restrict__ wmf,
    float* __restrict__ r2out) {
  const int b = blockIdx.x;
  if (b < 2500) {
    const int t = b * 256 + threadIdx.x;
    const int row = t >> 4;   // 16 lanes per row
    const int sub = t & 15;
    float4 v = reinterpret_cast<const float4*>(x + (size_t)row * IN_DIM)[sub];
    float s = (v.x + v.y) + (v.z + v.w);
    s += __shfl_xor(s, 1, 64);
    s += __shfl_xor(s, 2, 64);
    s += __shfl_xor(s, 4, 64);
    s += __shfl_xor(s, 8, 64);
    if (sub == 0) {
      float4 pkt;
      pkt.x = s_pts[row * 3 + 0];
      pkt.y = s_pts[row * 3 + 1];
      pkt.z = s_pts[row * 3 + 2];
      pkt.w = (s > 0.0f) ? 1.0f : 0.0f;
      packed[row] = pkt;
    }
    if (t == 1) {   // shadow support point: origin, invalid
      float4 z; z.x = 0.f; z.y = 0.f; z.z = 0.f; z.w = 0.f;
      packed[N_S] = z;
    }
  } else if (b < 2740) {
    // one uint (2 bf16, consecutive k) per thread; flat index t matches
    // uint4 index fi*64+lane used by the consumer (t = fi*256 + lane*4 + j2)
    const int t = (b - 2500) * 256 + threadIdx.x;   // 0..61439
    const int j2   = t & 3;
    const int lane = (t >> 2) & 63;
    const int fi   = t >> 8;            // (p*8+g)*2+kc, 0..239
    const int kc = fi & 1, g = (fi >> 1) & 7, p = fi >> 4;
    const int c  = g * 16 + (lane & 15);
    const int k0 = kc * 32 + (lane >> 4) * 8 + 2 * j2;
    const float w0 = weights[(size_t)p * (IN_DIM * OUT_DIM) + (size_t)k0 * OUT_DIM + c];
    const float w1 = weights[(size_t)p * (IN_DIM * OUT_DIM) + (size_t)(k0 + 1) * OUT_DIM + c];
    wmf[t] = (unsigned)(unsigned short)f2bf(w0)
           | ((unsigned)(unsigned short)f2bf(w1) << 16);
  } else {
    // R2 = (max_p |kp| + KP_EXTENT)^2, computed once (identical value to the
    // per-wave reduction the hot kernel used to do)
    if (threadIdx.x < 64) {
      const int lane = threadIdx.x;
      float r2 = 0.0f;
      if (lane < PP) {
        const float kx = kpts[lane * 3 + 0];
        const float ky = kpts[lane * 3 + 1];
        const float kz = kpts[lane * 3 + 2];
        r2 = kx * kx + ky * ky + kz * kz;
      }
      #pragma unroll
      for (int s = 32; s; s >>= 1) r2 = fmaxf(r2, __shfl_xor(r2, s, 64));
      if (lane == 0) {
        const float R = sqrtf(r2) + 0.05f;
        r2out[0] = R * R;
      }
    }
  }
}

// Kernel 2 (fused): one thread per (query, neighbor); lanes 0-31 = query A,
// 32-63 = query B. Lane l (<15) owns kernel point l in registers. Per thread:
// one ball early-out test; candidates (~3/wave) are processed wave-cooperatively
// (lanes 0-14 evaluate all 15 distances at once); each rare hit runs 16 MFMAs
// (rows 0/1 = queries A/B) against the pre-swizzled bf16 W. Output written
// exactly once by lanes 0-15 from the mfma accumulators.
__global__ __launch_bounds__(256, 4) void kpconv_fused_kernel(
    const float* __restrict__ q_pts, const int* __restrict__ nidx,
    const float* __restrict__ x, const float* __restrict__ kpts,
    const float4* __restrict__ packed, const uint4* __restrict__ wmf4,
    const float* __restrict__ r2buf, float* __restrict__ out) {
  const int tid  = blockIdx.x * 256 + threadIdx.x;
  const int lane = threadIdx.x & 63;
  const int n  = tid >> 5;            // this lane's query
  const int nA = (tid & ~63) >> 5;    // wave's first query

  // lane-resident kernel point (lanes >=15 duplicate point 0)
  const int pl = (lane < PP) ? lane : 0;
  const float kxl = kpts[pl * 3 + 0];
  const float kyl = kpts[pl * 3 + 1];
  const float kzl = kpts[pl * 3 + 2];

  // candidate radius^2: precomputed in prep (uniform load -> scalar)
  const float R2 = r2buf[0];

  const int id = nidx[tid];           // coalesced; id in [0, N_S]
  const float4 sp = packed[id];       // ONE divergent 16B gather
  const bool real = (id < N_S);

  const float ox = sp.x - q_pts[n * 3 + 0];
  const float oy = sp.y - q_pts[n * 3 + 1];
  const float oz = sp.z - q_pts[n * 3 + 2];

  // neighbor_num per query (shadow entry has sp.w == 0)
  unsigned long long bal = __ballot(sp.w != 0.0f);
  unsigned int half = (lane < 32) ? (unsigned int)bal
                                  : (unsigned int)(bal >> 32);
  int num = (int)__popc(half);
  if (num < 1) num = 1;
  const float invnum = 1.0f / (float)num;

  floatx4 acc[8];
  #pragma unroll
  for (int g = 0; g < 8; ++g) acc[g] = (floatx4){0.f, 0.f, 0.f, 0.f};

  const float d2o = ox * ox + oy * oy + oz * oz;
  unsigned long long bc = __ballot(real && (d2o <= R2));
  while (bc) {
    const int j = (int)__ffsll((unsigned long long)bc) - 1;
    bc &= bc - 1;
    const float oxj = __shfl(ox, j);
    const float oyj = __shfl(oy, j);
    const float ozj = __shfl(oz, j);
    const int   idj = __shfl(id, j);
    const float inj = __shfl(invnum, j);
    // lanes 0-14 evaluate all 15 kernel points for candidate j in parallel
    const float dx = oxj - kxl, dy = oyj - kyl, dz = ozj - kzl;
    const float d2 = dx * dx + dy * dy + dz * dz;
    const bool hit = (lane < PP) && (d2 < 0.0025f);
    const float wc = hit ? (1.0f - 20.0f * sqrtf(d2)) * inj : 0.0f;
    unsigned long long bh = __ballot(hit);
    const int m = j >> 5;   // 0: query A, 1: query B
    while (bh) {
      const int h = (int)__ffsll((unsigned long long)bh) - 1;
      bh &= bh - 1;
      const float wj = __shfl(wc, h);
      const int p = h;
      // A fragments (rows: m only): A[m][k=quad*8+e(+32)] = wj * x[idj][k]
      short8 af0 = {0, 0, 0, 0, 0, 0, 0, 0};
      short8 af1 = {0, 0, 0, 0, 0, 0, 0, 0};
      if ((lane & 15) == m) {
        const float4* xr = reinterpret_cast<const float4*>(x + (size_t)idj * IN_DIM);
        const int q4 = (lane >> 4) * 2;
        const float4 xa = xr[q4],     xb = xr[q4 + 1];   // k-chunk 0
        const float4 xc = xr[q4 + 8], xd = xr[q4 + 9];   // k-chunk 1
        af0[0] = f2bf(wj * xa.x); af0[1] = f2bf(wj * xa.y);
        af0[2] = f2bf(wj * xa.z); af0[3] = f2bf(wj * xa.w);
        af0[4] = f2bf(wj * xb.x); af0[5] = f2bf(wj * xb.y);
        af0[6] = f2bf(wj * xb.z); af0[7] = f2bf(wj * xb.w);
        af1[0] = f2bf(wj * xc.x); af1[1] = f2bf(wj * xc.y);
        af1[2] = f2bf(wj * xc.z); af1[3] = f2bf(wj * xc.w);
        af1[4] = f2bf(wj * xd.x); af1[5] = f2bf(wj * xd.y);
        af1[6] = f2bf(wj * xd.z); af1[7] = f2bf(wj * xd.w);
      }
      #pragma unroll
      for (int g = 0; g < 8; ++g) {
        const uint4 b0 = wmf4[(size_t)((p * 8 + g) * 2 + 0) * 64 + lane];
        acc[g] = __builtin_amdgcn_mfma_f32_16x16x32_bf16(
            af0, __builtin_bit_cast(short8, b0), acc[g], 0, 0, 0);
        const uint4 b1 = wmf4[(size_t)((p * 8 + g) * 2 + 1) * 64 + lane];
        acc[g] = __builtin_amdgcn_mfma_f32_16x16x32_bf16(
            af1, __builtin_bit_cast(short8, b1), acc[g], 0, 0, 0);
      }
    }
  }

  // D layout: col = lane&15, row = (lane>>4)*4 + reg -> rows 0/1 live in
  // lanes 0-15, regs 0/1. Zero-hit queries write zeros (correct: 0/num).
  if (lane < 16) {
    #pragma unroll
    for (int g = 0; g < 8; ++g) {
      out[(size_t)nA * OUT_DIM + g * 16 + lane]       = acc[g][0];
      out[(size_t)(nA + 1) * OUT_DIM + g * 16 + lane] = acc[g][1];
    }
  }
}

extern "C" void kernel_launch(void* const* d_in, const int* in_sizes, int n_in,
                              void* d_out, int out_size, void* d_ws, size_t ws_size,
                              hipStream_t stream) {
  const float* q_pts   = (const float*)d_in[0];
  const float* s_pts   = (const float*)d_in[1];
  const int*   nidx    = (const int*)d_in[2];
  const float* x       = (const float*)d_in[3];
  const float* weights = (const float*)d_in[4];
  const float* kpts    = (const float*)d_in[5];
  float* out = (float*)d_out;

  char* ws = (char*)d_ws;
  float4*   packed = (float4*)ws;                     // (N_S+1)*16 B = 640 KB
  unsigned* wmf    = (unsigned*)(ws + (1u << 20));    // 240 KB, mfma B-frag order
  float*    r2buf  = (float*)(ws + (1u << 20) + (256u << 10));

  prep_kernel<<<2741, 256, 0, stream>>>(x, s_pts, weights, kpts, packed, wmf, r2buf);
  kpconv_fused_kernel<<<(N_Q * KK) / 256, 256, 0, stream>>>(
      q_pts, nidx, x, kpts, packed, (const uint4*)wmf, r2buf, out);
}